// Round 1
// baseline (1187.924 us; speedup 1.0000x reference)
//
#include <hip/hip_runtime.h>

// Blur (stylegan2 upfirdn2d, up=1, down=1, pad=(1,1)) on (4,128,513,513) f32.
// Output (4,128,512,512). Kernel is rank-1 (outer product of [1,3,3,1]/4),
// so we run a fused separable 4-tap H + 4-tap V pass through LDS.
//
// Tile: 256 output cols x 32 output rows per block (one (n,c) plane slice).
// LDS stage: 35 rows x 259 cols = 36.3 KB  -> 4 blocks/CU, 16 waves/CU.

#define TW 256          // output cols per block
#define TH 32           // output rows per block
#define HALO_W (TW + 3) // 259
#define HALO_H (TH + 3) // 35

#define W_IN  513
#define H_IN  513
#define W_OUT 512
#define H_OUT 512
#define IN_PLANE  (513 * 513)  // 263169
#define OUT_PLANE (512 * 512)  // 262144

__global__ __launch_bounds__(256)
void blur_kernel(const float* __restrict__ in,
                 const float* __restrict__ kern,
                 float* __restrict__ out) {
    __shared__ float lds[HALO_H][HALO_W];

    const int t  = threadIdx.x;
    const int x0 = blockIdx.x * TW;
    const int y0 = blockIdx.y * TH;
    const int p  = blockIdx.z;

    const float* ip = in  + (size_t)p * IN_PLANE;
    float*       op = out + (size_t)p * OUT_PLANE;

    // Reference flips the kernel: wf[i][j] = kern[3-i][3-j].
    // Separable factors (kern is rank-1): kx[j] = wf[1][j], a[i] = wf[i][1]/wf[1][1].
    // These are uniform scalar loads (L2-cached, negligible).
    const float kx0 = kern[2 * 4 + 3];   // wf[1][0]
    const float kx1 = kern[2 * 4 + 2];   // wf[1][1]
    const float kx2 = kern[2 * 4 + 1];   // wf[1][2]
    const float kx3 = kern[2 * 4 + 0];   // wf[1][3]
    const float inv = 1.0f / kern[2 * 4 + 2];
    const float a0  = kern[3 * 4 + 2] * inv;  // wf[0][1]/wf[1][1]
    const float a1  = 1.0f;                   // wf[1][1]/wf[1][1]
    const float a2  = kern[1 * 4 + 2] * inv;  // wf[2][1]/wf[1][1]
    const float a3  = kern[0 * 4 + 2] * inv;  // wf[3][1]/wf[1][1]

    // ---- Stage input tile (rows y0-1 .. y0+33, cols x0-1 .. x0+257) ----
    const int col   = x0 - 1 + t;
    const bool cv   = (col >= 0) && (col < W_IN);
    const int col2  = col + TW;            // only threads 0..2 use this
    const bool cv2  = (col2 < W_IN);       // col2 >= 255, always >= 0

    for (int r = 0; r < HALO_H; ++r) {
        const int  row = y0 - 1 + r;
        const bool rv  = (row >= 0) && (row < H_IN);
        const int  rb  = row * W_IN;
        float v = 0.0f;
        if (rv && cv) v = ip[rb + col];
        lds[r][t] = v;
        if (t < 3) {
            float v2 = 0.0f;
            if (rv && cv2) v2 = ip[rb + col2];
            lds[r][t + TW] = v2;
        }
    }
    __syncthreads();

    // ---- Horizontal 4-tap (consecutive-lane LDS reads: conflict-free) ----
    float h[HALO_H];
#pragma unroll
    for (int r = 0; r < HALO_H; ++r) {
        h[r] = lds[r][t]     * kx0
             + lds[r][t + 1] * kx1
             + lds[r][t + 2] * kx2
             + lds[r][t + 3] * kx3;
    }

    // ---- Vertical 4-tap + coalesced store ----
#pragma unroll
    for (int r = 0; r < TH; ++r) {
        const float v = h[r] * a0 + h[r + 1] * a1 + h[r + 2] * a2 + h[r + 3] * a3;
        op[(y0 + r) * W_OUT + x0 + t] = v;
    }
}

extern "C" void kernel_launch(void* const* d_in, const int* in_sizes, int n_in,
                              void* d_out, int out_size, void* d_ws, size_t ws_size,
                              hipStream_t stream) {
    const float* x    = (const float*)d_in[0];  // (4,128,513,513) f32
    const float* kern = (const float*)d_in[1];  // (4,4) f32
    float* out        = (float*)d_out;          // (4,128,512,512) f32

    // planes = N*C = 512; col tiles = 512/256 = 2; row tiles = 512/32 = 16
    dim3 grid(W_OUT / TW, H_OUT / TH, 4 * 128);
    dim3 block(256, 1, 1);
    blur_kernel<<<grid, block, 0, stream>>>(x, kern, out);
}